// Round 1
// baseline (1341.571 us; speedup 1.0000x reference)
//
#include <hip/hip_runtime.h>
#include <hip/hip_bf16.h>
#include <math.h>

// Problem constants
#define BATCH   65536L
#define EDIM    512
#define QKVDIM  1536
#define CONCATD 1024
#define HIDD    512
#define OUTD    256

typedef __bf16 bf16_t;
typedef __bf16 bf16x8 __attribute__((ext_vector_type(8)));
typedef __bf16 bf16x4 __attribute__((ext_vector_type(4)));
typedef float  floatx4 __attribute__((ext_vector_type(4)));

static_assert(sizeof(bf16x8) == 16, "bf16x8 must be 16B");

__device__ __forceinline__ void gload16(const void* g, void* l) {
  __builtin_amdgcn_global_load_lds(
      (__attribute__((address_space(1))) void*)(g),
      (__attribute__((address_space(3))) void*)(l), 16, 0, 0);
}

// ---------- convert inputs: interleave visual/text rows -> token-major bf16 ----------
__global__ __launch_bounds__(256) void convert_x_kernel(
    const float* __restrict__ vis, const float* __restrict__ txt,
    bf16_t* __restrict__ dst) {
  long idx = (long)blockIdx.x * 256 + threadIdx.x;
  long t = idx >> 6;            // local token
  int  c = (int)(idx & 63) * 8;
  long b = t >> 1;              // local batch row
  const float* src = ((t & 1) ? txt : vis) + b * EDIM + c;
  float4 f0 = *(const float4*)src;
  float4 f1 = *(const float4*)(src + 4);
  bf16x8 o;
  o[0] = (bf16_t)f0.x; o[1] = (bf16_t)f0.y; o[2] = (bf16_t)f0.z; o[3] = (bf16_t)f0.w;
  o[4] = (bf16_t)f1.x; o[5] = (bf16_t)f1.y; o[6] = (bf16_t)f1.z; o[7] = (bf16_t)f1.w;
  *(bf16x8*)(dst + t * EDIM + c) = o;
}

// ---------- convert weights fp32 -> bf16: wq (786432) | w2 (131072) ----------
__global__ __launch_bounds__(256) void convert_w_kernel(
    const float* __restrict__ wq, const float* __restrict__ w2,
    bf16_t* __restrict__ dst) {
  long idx = ((long)blockIdx.x * 256 + threadIdx.x) * 8;  // 917504 elems total
  const long n0 = 786432;
  const float* src; long off;
  if (idx < n0) { src = wq; off = idx; }
  else          { src = w2; off = idx - n0; }
  float4 f0 = *(const float4*)(src + off);
  float4 f1 = *(const float4*)(src + off + 4);
  bf16x8 o;
  o[0] = (bf16_t)f0.x; o[1] = (bf16_t)f0.y; o[2] = (bf16_t)f0.z; o[3] = (bf16_t)f0.w;
  o[4] = (bf16_t)f1.x; o[5] = (bf16_t)f1.y; o[6] = (bf16_t)f1.z; o[7] = (bf16_t)f1.w;
  *(bf16x8*)(dst + idx) = o;
}

// ---------- fold out_proj into mlp1: Wc[n, e] (512 x 1024) bf16 ----------
// Wc[n, e<512]    = sum_f W1[n, f]       * Wo[f, e]
// Wc[n, 512 + e]  = sum_f W1[n, 512 + f] * Wo[f, e]
// grid: 512 blocks (one per n), 256 threads, 4 outputs each
__global__ __launch_bounds__(256) void wc_kernel(
    const float* __restrict__ w1, const float* __restrict__ wo,
    bf16_t* __restrict__ wc) {
  int n = blockIdx.x;
  int t = threadIdx.x;
  const float* w1v = w1 + (long)n * 1024;
  const float* w1t = w1v + 512;
  float a0 = 0.f, a1 = 0.f, a2 = 0.f, a3 = 0.f;
  for (int f = 0; f < 512; f++) {
    float wv = w1v[f], wt = w1t[f];
    float x0 = wo[f * 512 + t], x1 = wo[f * 512 + t + 256];
    a0 += wv * x0; a1 += wv * x1;
    a2 += wt * x0; a3 += wt * x1;
  }
  bf16_t* out = wc + (long)n * 1024;
  out[t]        = (bf16_t)a0;
  out[t + 256]  = (bf16_t)a1;
  out[t + 512]  = (bf16_t)a2;
  out[t + 768]  = (bf16_t)a3;
}

// ---------- folded bias: bc[n] = b1[n] + sum_f (W1[n,f]+W1[n,512+f]) * bo[f] ----------
__global__ __launch_bounds__(256) void bc_kernel(
    const float* __restrict__ w1, const float* __restrict__ bo,
    const float* __restrict__ b1, float* __restrict__ bc) {
  int n = blockIdx.x * 256 + threadIdx.x;   // grid 2 x 256
  const float* w1row = w1 + (long)n * 1024;
  float acc = b1[n];
  for (int f = 0; f < 512; f++)
    acc += (w1row[f] + w1row[512 + f]) * bo[f];
  bc[n] = acc;
}

// ---------- m97-style bf16 GEMM + LDS xor-swizzle: C = A @ Bt^T + bias ----------
// EPI: 0 = bias only, 1 = bias + exact gelu
// LDS layout: physical chunk slot q_p at row r holds logical k-chunk q_p ^ ((r>>1)&3)
template<int EPI>
__global__ __launch_bounds__(256) void gemm_bt_kernel(
    const bf16_t* __restrict__ A, const bf16_t* __restrict__ Bt,
    const float* __restrict__ bias, bf16_t* __restrict__ C,
    int M, int N, int K, int ntiles) {
  __shared__ __attribute__((aligned(16))) bf16_t sA[128 * 32];
  __shared__ __attribute__((aligned(16))) bf16_t sB[128 * 32];
  const int bid  = blockIdx.x;
  const int mt   = bid / ntiles;
  const int nt   = bid % ntiles;
  const int tid  = threadIdx.x;
  const int wave = tid >> 6;
  const int lane = tid & 63;
  const int wm   = wave >> 1;   // 2x2 wave grid, each 64x64
  const int wn   = wave & 1;

  floatx4 acc[4][4];
  #pragma unroll
  for (int i = 0; i < 4; i++)
    #pragma unroll
    for (int j = 0; j < 4; j++) acc[i][j] = (floatx4){0.f, 0.f, 0.f, 0.f};

  // staging: lane l -> LDS base + l*16B = physical (row srow, chunk lane&3).
  // load the LOGICAL chunk that belongs in that slot: (lane&3) ^ ((srow>>1)&3)
  //   srow = wave*16 + (lane>>2)  =>  (srow>>1)&3 == (lane>>3)&3
  const int srow = wave * 16 + (lane >> 2);
  const int scol = (((lane & 3) ^ ((lane >> 3) & 3)) * 8);
  const bf16_t* Ag0 = A  + (long)(mt * 128 + srow) * K + scol;
  const bf16_t* Ag1 = Ag0 + 64L * K;
  const bf16_t* Bg0 = Bt + (long)(nt * 128 + srow) * K + scol;
  const bf16_t* Bg1 = Bg0 + 64L * K;
  bf16_t* sA0 = sA + wave * 512;
  bf16_t* sA1 = sA + 2048 + wave * 512;
  bf16_t* sB0 = sB + wave * 512;
  bf16_t* sB1 = sB + 2048 + wave * 512;

  const int m_l = lane & 15;
  // read side: logical chunk lane>>4 at row r -> physical (lane>>4) ^ ((r>>1)&3);
  // (r>>1)&3 == (m_l>>1)&3 for all i (row = wm*64 + i*16 + m_l)
  const int kq = (((lane >> 4) ^ ((m_l >> 1) & 3)) * 8);

  for (int k0 = 0; k0 < K; k0 += 32) {
    __syncthreads();          // previous iteration's LDS reads complete
    gload16(Ag0 + k0, sA0);
    gload16(Ag1 + k0, sA1);
    gload16(Bg0 + k0, sB0);
    gload16(Bg1 + k0, sB1);
    __syncthreads();          // staging complete

    bf16x8 a[4], b[4];
    #pragma unroll
    for (int i = 0; i < 4; i++)
      a[i] = *(const bf16x8*)&sA[(wm * 64 + i * 16 + m_l) * 32 + kq];
    #pragma unroll
    for (int j = 0; j < 4; j++)
      b[j] = *(const bf16x8*)&sB[(wn * 64 + j * 16 + m_l) * 32 + kq];
    #pragma unroll
    for (int i = 0; i < 4; i++)
      #pragma unroll
      for (int j = 0; j < 4; j++)
        acc[i][j] = __builtin_amdgcn_mfma_f32_16x16x32_bf16(a[i], b[j], acc[i][j], 0, 0, 0);
  }

  // epilogue: C/D layout col=lane&15, row=(lane>>4)*4+reg  [m89-verified]
  const int col_l = lane & 15;
  const int row_q = (lane >> 4) * 4;
  float bj[4];
  #pragma unroll
  for (int j = 0; j < 4; j++)
    bj[j] = bias[nt * 128 + wn * 64 + j * 16 + col_l];
  #pragma unroll
  for (int i = 0; i < 4; i++) {
    #pragma unroll
    for (int r = 0; r < 4; r++) {
      long row = (long)(mt * 128 + wm * 64 + i * 16 + row_q + r);
      bf16_t* crow = C + row * N + nt * 128 + wn * 64 + col_l;
      #pragma unroll
      for (int j = 0; j < 4; j++) {
        float v = acc[i][j][r] + bj[j];
        if (EPI == 1) v = 0.5f * v * (1.0f + erff(v * 0.70710678118654752f));
        crow[j * 16] = (bf16_t)v;
      }
    }
  }
}

// ---------- attention: per (row, head) 2x2 softmax + ctx; head-mean weights ----------
__global__ __launch_bounds__(256) void attn_kernel(
    const bf16_t* __restrict__ qkv, bf16_t* __restrict__ ctx,
    float* __restrict__ wout) {
  long idx = (long)blockIdx.x * 256 + threadIdx.x;
  long b = idx >> 3;   // local batch row
  int  h = (int)(idx & 7);
  const bf16_t* base = qkv + (b * 2) * QKVDIM + h * 64;
  const bf16_t* q0 = base;
  const bf16_t* q1 = base + QKVDIM;
  const bf16_t* k0 = base + EDIM;
  const bf16_t* k1 = base + EDIM + QKVDIM;
  const bf16_t* v0 = base + 2 * EDIM;
  const bf16_t* v1 = base + 2 * EDIM + QKVDIM;

  float s00 = 0.f, s01 = 0.f, s10 = 0.f, s11 = 0.f;
  #pragma unroll
  for (int c = 0; c < 64; c += 8) {
    bf16x8 a0 = *(const bf16x8*)(q0 + c), a1 = *(const bf16x8*)(q1 + c);
    bf16x8 c0 = *(const bf16x8*)(k0 + c), c1 = *(const bf16x8*)(k1 + c);
    #pragma unroll
    for (int r = 0; r < 8; r++) {
      float x0 = (float)a0[r], x1 = (float)a1[r];
      float y0 = (float)c0[r], y1 = (float)c1[r];
      s00 += x0 * y0; s01 += x0 * y1; s10 += x1 * y0; s11 += x1 * y1;
    }
  }
  const float sc = 0.125f;  // 1/sqrt(64)
  s00 *= sc; s01 *= sc; s10 *= sc; s11 *= sc;
  float m0 = fmaxf(s00, s01), m1 = fmaxf(s10, s11);
  float e00 = __expf(s00 - m0), e01 = __expf(s01 - m0);
  float e10 = __expf(s10 - m1), e11 = __expf(s11 - m1);
  float d0 = e00 + e01, d1 = e10 + e11;
  float a00 = e00 / d0, a01 = e01 / d0, a10 = e10 / d1, a11 = e11 / d1;

  // weights = attn.mean over heads; 8 heads live in 8 adjacent lanes
  float r00 = a00, r01 = a01, r10 = a10, r11 = a11;
  #pragma unroll
  for (int mask = 1; mask < 8; mask <<= 1) {
    r00 += __shfl_xor(r00, mask);
    r01 += __shfl_xor(r01, mask);
    r10 += __shfl_xor(r10, mask);
    r11 += __shfl_xor(r11, mask);
  }
  if (h == 0) {
    float4 wv = make_float4(r00 * 0.125f, r01 * 0.125f, r10 * 0.125f, r11 * 0.125f);
    *(float4*)(wout + b * 4) = wv;
  }

  bf16_t* o0 = ctx + (b * 2) * EDIM + h * 64;
  bf16_t* o1 = o0 + EDIM;
  #pragma unroll
  for (int c = 0; c < 64; c += 8) {
    bf16x8 x0 = *(const bf16x8*)(v0 + c), x1 = *(const bf16x8*)(v1 + c);
    bf16x8 t0, t1;
    #pragma unroll
    for (int r = 0; r < 8; r++) {
      float f0 = (float)x0[r], f1 = (float)x1[r];
      t0[r] = (bf16_t)(a00 * f0 + a01 * f1);
      t1[r] = (bf16_t)(a10 * f0 + a11 * f1);
    }
    *(bf16x8*)(o0 + c) = t0;
    *(bf16x8*)(o1 + c) = t1;
  }
}

// ---------- LayerNorm over OUTD=256: one wave per row ----------
__global__ __launch_bounds__(256) void ln_kernel(
    const bf16_t* __restrict__ O, const float* __restrict__ gamma,
    const float* __restrict__ beta, float* __restrict__ out) {
  int  tid  = threadIdx.x;
  long row  = (long)blockIdx.x * 4 + (tid >> 6);
  int  lane = tid & 63;
  bf16x4 ov = *(const bf16x4*)(O + row * OUTD + lane * 4);
  float v0 = (float)ov[0], v1 = (float)ov[1], v2 = (float)ov[2], v3 = (float)ov[3];
  float s  = v0 + v1 + v2 + v3;
  float s2 = v0 * v0 + v1 * v1 + v2 * v2 + v3 * v3;
  #pragma unroll
  for (int mask = 1; mask < 64; mask <<= 1) {
    s  += __shfl_xor(s, mask);
    s2 += __shfl_xor(s2, mask);
  }
  float mu  = s * (1.0f / 256.0f);
  float var = s2 * (1.0f / 256.0f) - mu * mu;
  float rs  = rsqrtf(var + 1e-5f);
  float4 g  = *(const float4*)(gamma + lane * 4);
  float4 be = *(const float4*)(beta + lane * 4);
  float4 res;
  res.x = (v0 - mu) * rs * g.x + be.x;
  res.y = (v1 - mu) * rs * g.y + be.y;
  res.z = (v2 - mu) * rs * g.z + be.z;
  res.w = (v3 - mu) * rs * g.w + be.w;
  *(float4*)(out + row * OUTD + lane * 4) = res;
}

extern "C" void kernel_launch(void* const* d_in, const int* in_sizes, int n_in,
                              void* d_out, int out_size, void* d_ws, size_t ws_size,
                              hipStream_t stream) {
  (void)in_sizes; (void)n_in; (void)out_size;
  const float* vis   = (const float*)d_in[0];
  const float* txt   = (const float*)d_in[1];
  const float* w_qkv = (const float*)d_in[2];
  const float* b_qkv = (const float*)d_in[3];
  const float* w_out = (const float*)d_in[4];
  const float* b_out = (const float*)d_in[5];
  const float* w1    = (const float*)d_in[6];
  const float* b1    = (const float*)d_in[7];
  const float* w2    = (const float*)d_in[8];
  const float* b2    = (const float*)d_in[9];
  const float* gamma = (const float*)d_in[10];
  const float* beta  = (const float*)d_in[11];
  float* out_fused   = (float*)d_out;
  float* out_weights = out_fused + BATCH * OUTD;

  char* ws = (char*)d_ws;
  const size_t MB = 1024 * 1024;

  // chunked pipeline: footprint = 4MB weights + 8192*Bc bytes
  //   region1 (2048*Bc): X -> CTX -> O
  //   region2 (6144*Bc): QKV -> H
  // Bc clamp: (a) fit workspace, (b) fit Infinity Cache (L3, 256MB).
  //   Bc=8192 -> chunk intermediates = 16.8MB (reg1) + 50MB (reg2) + 4MB
  //   weights ~= 71MB; regions are reused at the SAME addresses every chunk,
  //   so QKV/CTX/H/O round-trips stay L3-resident instead of hitting HBM
  //   (at Bc=32768 the 260MB working set thrashed L3: QKV gemm FETCH was
  //   4x its compulsory A-read).
  long Bc = BATCH;
  int  nch = 1;
  while (((size_t)(4 * MB) + (size_t)(8192UL * (unsigned long)Bc) > ws_size
          || Bc > 8192) && nch < 64) {
    Bc >>= 1; nch <<= 1;
  }

  // bf16 weights: wq (786432) | w2 (131072) | wc (524288) ; bc fp32 at +3MB
  bf16_t* wq_b = (bf16_t*)ws;
  bf16_t* w2_b = wq_b + 786432;
  bf16_t* wc_b = wq_b + 917504;
  float*  bc   = (float*)(ws + 3 * MB);
  convert_w_kernel<<<448, 256, 0, stream>>>(w_qkv, w2, wq_b);
  wc_kernel<<<512, 256, 0, stream>>>(w1, w_out, wc_b);
  bc_kernel<<<2, 256, 0, stream>>>(w1, b_out, b1, bc);

  bf16_t* reg1 = (bf16_t*)(ws + 4 * MB);                     // 2048*Bc bytes
  bf16_t* reg2 = (bf16_t*)(ws + 4 * MB + (size_t)2048 * Bc); // 6144*Bc bytes

  const long Tc = 2 * Bc;  // tokens per chunk
  for (int c = 0; c < nch; c++) {
    const float* visc = vis + (long)c * Bc * EDIM;
    const float* txtc = txt + (long)c * Bc * EDIM;
    bf16_t* X   = reg1;   // Tc x 512
    bf16_t* QKV = reg2;   // Tc x 1536
    bf16_t* CTX = reg1;   // Tc x 512 (X dead after QKV gemm); == flat Bc x 1024
    bf16_t* H   = reg2;   // Bc x 512 (QKV dead after attn)
    bf16_t* O   = reg1;   // Bc x 256 (CTX dead after mlp1)

    convert_x_kernel<<<(int)(Tc / 4), 256, 0, stream>>>(visc, txtc, X);
    // QKV: (Tc x 512) @ (1536 x 512)^T
    gemm_bt_kernel<0><<<(int)(Tc / 128) * 12, 256, 0, stream>>>(
        X, wq_b, b_qkv, QKV, (int)Tc, QKVDIM, EDIM, 12);
    attn_kernel<<<(int)(Bc / 32), 256, 0, stream>>>(
        QKV, CTX, out_weights + (long)c * Bc * 4);
    // MLP1' (out_proj folded) + gelu: (Bc x 1024) @ (512 x 1024)^T
    gemm_bt_kernel<1><<<(int)(Bc / 128) * 4, 256, 0, stream>>>(
        CTX, wc_b, bc, H, (int)Bc, HIDD, CONCATD, 4);
    // MLP2: (Bc x 512) @ (256 x 512)^T
    gemm_bt_kernel<0><<<(int)(Bc / 128) * 2, 256, 0, stream>>>(
        H, w2_b, b2, O, (int)Bc, OUTD, HIDD, 2);
    ln_kernel<<<(int)(Bc / 4), 256, 0, stream>>>(
        O, gamma, beta, out_fused + (long)c * Bc * OUTD);
  }
}

// Round 2
// 1184.577 us; speedup vs baseline: 1.1325x; 1.1325x over previous
//
#include <hip/hip_runtime.h>
#include <hip/hip_bf16.h>
#include <math.h>

// Problem constants
#define BATCH   65536L
#define EDIM    512
#define QKVDIM  1536
#define CONCATD 1024
#define HIDD    512
#define OUTD    256

typedef __bf16 bf16_t;
typedef __bf16 bf16x8 __attribute__((ext_vector_type(8)));
typedef __bf16 bf16x4 __attribute__((ext_vector_type(4)));
typedef float  floatx4 __attribute__((ext_vector_type(4)));

static_assert(sizeof(bf16x8) == 16, "bf16x8 must be 16B");

__device__ __forceinline__ void gload16(const void* g, void* l) {
  __builtin_amdgcn_global_load_lds(
      (__attribute__((address_space(1))) void*)(g),
      (__attribute__((address_space(3))) void*)(l), 16, 0, 0);
}

// ---------- convert inputs: interleave visual/text rows -> token-major bf16 ----------
__global__ __launch_bounds__(256) void convert_x_kernel(
    const float* __restrict__ vis, const float* __restrict__ txt,
    bf16_t* __restrict__ dst) {
  long idx = (long)blockIdx.x * 256 + threadIdx.x;
  long t = idx >> 6;            // local token
  int  c = (int)(idx & 63) * 8;
  long b = t >> 1;              // local batch row
  const float* src = ((t & 1) ? txt : vis) + b * EDIM + c;
  float4 f0 = *(const float4*)src;
  float4 f1 = *(const float4*)(src + 4);
  bf16x8 o;
  o[0] = (bf16_t)f0.x; o[1] = (bf16_t)f0.y; o[2] = (bf16_t)f0.z; o[3] = (bf16_t)f0.w;
  o[4] = (bf16_t)f1.x; o[5] = (bf16_t)f1.y; o[6] = (bf16_t)f1.z; o[7] = (bf16_t)f1.w;
  *(bf16x8*)(dst + t * EDIM + c) = o;
}

// ---------- convert weights fp32 -> bf16: wq (786432) | w2 (131072) ----------
__global__ __launch_bounds__(256) void convert_w_kernel(
    const float* __restrict__ wq, const float* __restrict__ w2,
    bf16_t* __restrict__ dst) {
  long idx = ((long)blockIdx.x * 256 + threadIdx.x) * 8;  // 917504 elems total
  const long n0 = 786432;
  const float* src; long off;
  if (idx < n0) { src = wq; off = idx; }
  else          { src = w2; off = idx - n0; }
  float4 f0 = *(const float4*)(src + off);
  float4 f1 = *(const float4*)(src + off + 4);
  bf16x8 o;
  o[0] = (bf16_t)f0.x; o[1] = (bf16_t)f0.y; o[2] = (bf16_t)f0.z; o[3] = (bf16_t)f0.w;
  o[4] = (bf16_t)f1.x; o[5] = (bf16_t)f1.y; o[6] = (bf16_t)f1.z; o[7] = (bf16_t)f1.w;
  *(bf16x8*)(dst + idx) = o;
}

// ---------- fold out_proj into mlp1: Wc[n, e] (512 x 1024) bf16 ----------
__global__ __launch_bounds__(256) void wc_kernel(
    const float* __restrict__ w1, const float* __restrict__ wo,
    bf16_t* __restrict__ wc) {
  int n = blockIdx.x;
  int t = threadIdx.x;
  const float* w1v = w1 + (long)n * 1024;
  const float* w1t = w1v + 512;
  float a0 = 0.f, a1 = 0.f, a2 = 0.f, a3 = 0.f;
  for (int f = 0; f < 512; f++) {
    float wv = w1v[f], wt = w1t[f];
    float x0 = wo[f * 512 + t], x1 = wo[f * 512 + t + 256];
    a0 += wv * x0; a1 += wv * x1;
    a2 += wt * x0; a3 += wt * x1;
  }
  bf16_t* out = wc + (long)n * 1024;
  out[t]        = (bf16_t)a0;
  out[t + 256]  = (bf16_t)a1;
  out[t + 512]  = (bf16_t)a2;
  out[t + 768]  = (bf16_t)a3;
}

// ---------- folded bias: bc[n] = b1[n] + sum_f (W1[n,f]+W1[n,512+f]) * bo[f] ----------
__global__ __launch_bounds__(256) void bc_kernel(
    const float* __restrict__ w1, const float* __restrict__ bo,
    const float* __restrict__ b1, float* __restrict__ bc) {
  int n = blockIdx.x * 256 + threadIdx.x;   // grid 2 x 256
  const float* w1row = w1 + (long)n * 1024;
  float acc = b1[n];
  for (int f = 0; f < 512; f++)
    acc += (w1row[f] + w1row[512 + f]) * bo[f];
  bc[n] = acc;
}

// ---------- m97-style bf16 GEMM + LDS xor-swizzle: C = A @ Bt^T + bias ----------
// EPI: 0 = bias only, 1 = bias + exact gelu
// LDS layout: physical chunk slot q_p at row r holds logical k-chunk q_p ^ ((r>>1)&3)
template<int EPI>
__global__ __launch_bounds__(256) void gemm_bt_kernel(
    const bf16_t* __restrict__ A, const bf16_t* __restrict__ Bt,
    const float* __restrict__ bias, bf16_t* __restrict__ C,
    int M, int N, int K, int ntiles) {
  __shared__ __attribute__((aligned(16))) bf16_t sA[128 * 32];
  __shared__ __attribute__((aligned(16))) bf16_t sB[128 * 32];
  const int bid  = blockIdx.x;
  const int mt   = bid / ntiles;
  const int nt   = bid % ntiles;
  const int tid  = threadIdx.x;
  const int wave = tid >> 6;
  const int lane = tid & 63;
  const int wm   = wave >> 1;   // 2x2 wave grid, each 64x64
  const int wn   = wave & 1;

  floatx4 acc[4][4];
  #pragma unroll
  for (int i = 0; i < 4; i++)
    #pragma unroll
    for (int j = 0; j < 4; j++) acc[i][j] = (floatx4){0.f, 0.f, 0.f, 0.f};

  const int srow = wave * 16 + (lane >> 2);
  const int scol = (((lane & 3) ^ ((lane >> 3) & 3)) * 8);
  const bf16_t* Ag0 = A  + (long)(mt * 128 + srow) * K + scol;
  const bf16_t* Ag1 = Ag0 + 64L * K;
  const bf16_t* Bg0 = Bt + (long)(nt * 128 + srow) * K + scol;
  const bf16_t* Bg1 = Bg0 + 64L * K;
  bf16_t* sA0 = sA + wave * 512;
  bf16_t* sA1 = sA + 2048 + wave * 512;
  bf16_t* sB0 = sB + wave * 512;
  bf16_t* sB1 = sB + 2048 + wave * 512;

  const int m_l = lane & 15;
  const int kq = (((lane >> 4) ^ ((m_l >> 1) & 3)) * 8);

  for (int k0 = 0; k0 < K; k0 += 32) {
    __syncthreads();          // previous iteration's LDS reads complete
    gload16(Ag0 + k0, sA0);
    gload16(Ag1 + k0, sA1);
    gload16(Bg0 + k0, sB0);
    gload16(Bg1 + k0, sB1);
    __syncthreads();          // staging complete

    bf16x8 a[4], b[4];
    #pragma unroll
    for (int i = 0; i < 4; i++)
      a[i] = *(const bf16x8*)&sA[(wm * 64 + i * 16 + m_l) * 32 + kq];
    #pragma unroll
    for (int j = 0; j < 4; j++)
      b[j] = *(const bf16x8*)&sB[(wn * 64 + j * 16 + m_l) * 32 + kq];
    #pragma unroll
    for (int i = 0; i < 4; i++)
      #pragma unroll
      for (int j = 0; j < 4; j++)
        acc[i][j] = __builtin_amdgcn_mfma_f32_16x16x32_bf16(a[i], b[j], acc[i][j], 0, 0, 0);
  }

  // epilogue: C/D layout col=lane&15, row=(lane>>4)*4+reg  [m89-verified]
  const int col_l = lane & 15;
  const int row_q = (lane >> 4) * 4;
  float bj[4];
  #pragma unroll
  for (int j = 0; j < 4; j++)
    bj[j] = bias[nt * 128 + wn * 64 + j * 16 + col_l];
  #pragma unroll
  for (int i = 0; i < 4; i++) {
    #pragma unroll
    for (int r = 0; r < 4; r++) {
      long row = (long)(mt * 128 + wm * 64 + i * 16 + row_q + r);
      bf16_t* crow = C + row * N + nt * 128 + wn * 64 + col_l;
      #pragma unroll
      for (int j = 0; j < 4; j++) {
        float v = acc[i][j][r] + bj[j];
        if (EPI == 1) v = 0.5f * v * (1.0f + erff(v * 0.70710678118654752f));
        crow[j * 16] = (bf16_t)v;
      }
    }
  }
}

// ---------- fused MLP2 + LayerNorm: out = LN(H @ w2^T + b2) * gamma + beta ----------
// Tile: 64 rows x 256 cols (full N), K=512. 4 waves in 1x4 over N.
// Epilogue: fp32 O-tile in LDS (stride 260 floats), row stats via 4-thread
// shfl reduce, then coalesced fp32 write of the final output.
__global__ __launch_bounds__(256) void mlp2_ln_kernel(
    const bf16_t* __restrict__ A,   // Bc x 512
    const bf16_t* __restrict__ Bt,  // 256 x 512
    const float* __restrict__ bias, // b2
    const float* __restrict__ gamma, const float* __restrict__ beta,
    float* __restrict__ out) {      // Bc x 256 fp32
  __shared__ __attribute__((aligned(16))) char smem[67072];
  bf16_t* sA   = (bf16_t*)smem;             // 64 x 32  (4 KB)
  bf16_t* sB   = (bf16_t*)(smem + 4096);    // 256 x 32 (16 KB)
  float*  Ot   = (float*)smem;              // 64 x 260 fp32 (overlay, 65 KB)
  float*  mu_s = (float*)(smem + 66560);    // 64 floats
  float*  rs_s = (float*)(smem + 66816);    // 64 floats

  const int tid  = threadIdx.x;
  const int wave = tid >> 6;                // wn = wave (1x4 over N)
  const int lane = tid & 63;

  floatx4 acc[4][4];
  #pragma unroll
  for (int i = 0; i < 4; i++)
    #pragma unroll
    for (int j = 0; j < 4; j++) acc[i][j] = (floatx4){0.f, 0.f, 0.f, 0.f};

  const int srow = wave * 16 + (lane >> 2);       // rows 0..63 across 4 waves
  const int scol = (((lane & 3) ^ ((lane >> 3) & 3)) * 8);
  const bf16_t* Ag = A  + ((long)blockIdx.x * 64 + srow) * 512 + scol;
  const bf16_t* Bg = Bt + (long)srow * 512 + scol;
  bf16_t* sAw = sA + wave * 16 * 32;

  const int m_l = lane & 15;
  const int kq  = (((lane >> 4) ^ ((m_l >> 1) & 3)) * 8);

  for (int k0 = 0; k0 < 512; k0 += 32) {
    __syncthreads();
    gload16(Ag + k0, sAw);
    gload16(Bg + k0,              sB + (0   + wave * 16) * 32);
    gload16(Bg + 64L * 512 + k0,  sB + (64  + wave * 16) * 32);
    gload16(Bg + 128L * 512 + k0, sB + (128 + wave * 16) * 32);
    gload16(Bg + 192L * 512 + k0, sB + (192 + wave * 16) * 32);
    __syncthreads();

    bf16x8 a[4], b[4];
    #pragma unroll
    for (int i = 0; i < 4; i++)
      a[i] = *(const bf16x8*)&sA[(i * 16 + m_l) * 32 + kq];
    #pragma unroll
    for (int j = 0; j < 4; j++)
      b[j] = *(const bf16x8*)&sB[(wave * 64 + j * 16 + m_l) * 32 + kq];
    #pragma unroll
    for (int i = 0; i < 4; i++)
      #pragma unroll
      for (int j = 0; j < 4; j++)
        acc[i][j] = __builtin_amdgcn_mfma_f32_16x16x32_bf16(a[i], b[j], acc[i][j], 0, 0, 0);
  }

  // epilogue: scatter fp32 (acc + bias) into LDS O-tile
  const int col_l = lane & 15;
  const int row_q = (lane >> 4) * 4;
  float bj[4];
  #pragma unroll
  for (int j = 0; j < 4; j++)
    bj[j] = bias[wave * 64 + j * 16 + col_l];
  __syncthreads();  // sA/sB reads complete before overlay
  #pragma unroll
  for (int i = 0; i < 4; i++)
    #pragma unroll
    for (int r = 0; r < 4; r++)
      #pragma unroll
      for (int j = 0; j < 4; j++)
        Ot[(i * 16 + row_q + r) * 260 + wave * 64 + j * 16 + col_l] =
            acc[i][j][r] + bj[j];
  __syncthreads();

  // row stats: thread t covers row t>>2, quarter t&3 (64 cols)
  {
    int row = tid >> 2, q = tid & 3;
    const float* p = Ot + row * 260 + q * 64;
    float s = 0.f, s2 = 0.f;
    #pragma unroll
    for (int c = 0; c < 64; c += 4) {
      float4 v = *(const float4*)(p + c);
      s  += v.x + v.y + v.z + v.w;
      s2 += v.x * v.x + v.y * v.y + v.z * v.z + v.w * v.w;
    }
    s  += __shfl_xor(s, 1);  s  += __shfl_xor(s, 2);
    s2 += __shfl_xor(s2, 1); s2 += __shfl_xor(s2, 2);
    if (q == 0) {
      float mu  = s * (1.0f / 256.0f);
      float var = s2 * (1.0f / 256.0f) - mu * mu;
      mu_s[row] = mu;
      rs_s[row] = rsqrtf(var + 1e-5f);
    }
  }
  __syncthreads();

  // normalize + coalesced write: wave handles rows rr*4+wave; 1 KB/row/wave
  float4 g  = *(const float4*)(gamma + lane * 4);
  float4 be = *(const float4*)(beta + lane * 4);
  #pragma unroll
  for (int rr = 0; rr < 16; rr++) {
    int row = rr * 4 + wave;
    float mu = mu_s[row], rs = rs_s[row];
    float4 v = *(const float4*)(Ot + row * 260 + lane * 4);
    float4 res;
    res.x = (v.x - mu) * rs * g.x + be.x;
    res.y = (v.y - mu) * rs * g.y + be.y;
    res.z = (v.z - mu) * rs * g.z + be.z;
    res.w = (v.w - mu) * rs * g.w + be.w;
    *(float4*)(out + ((long)blockIdx.x * 64 + row) * 256 + lane * 4) = res;
  }
}

// ---------- attention: per (row, head) 2x2 softmax + ctx; head-mean weights ----------
__global__ __launch_bounds__(256) void attn_kernel(
    const bf16_t* __restrict__ qkv, bf16_t* __restrict__ ctx,
    float* __restrict__ wout) {
  long idx = (long)blockIdx.x * 256 + threadIdx.x;
  long b = idx >> 3;   // local batch row
  int  h = (int)(idx & 7);
  const bf16_t* base = qkv + (b * 2) * QKVDIM + h * 64;
  const bf16_t* q0 = base;
  const bf16_t* q1 = base + QKVDIM;
  const bf16_t* k0 = base + EDIM;
  const bf16_t* k1 = base + EDIM + QKVDIM;
  const bf16_t* v0 = base + 2 * EDIM;
  const bf16_t* v1 = base + 2 * EDIM + QKVDIM;

  float s00 = 0.f, s01 = 0.f, s10 = 0.f, s11 = 0.f;
  #pragma unroll
  for (int c = 0; c < 64; c += 8) {
    bf16x8 a0 = *(const bf16x8*)(q0 + c), a1 = *(const bf16x8*)(q1 + c);
    bf16x8 c0 = *(const bf16x8*)(k0 + c), c1 = *(const bf16x8*)(k1 + c);
    #pragma unroll
    for (int r = 0; r < 8; r++) {
      float x0 = (float)a0[r], x1 = (float)a1[r];
      float y0 = (float)c0[r], y1 = (float)c1[r];
      s00 += x0 * y0; s01 += x0 * y1; s10 += x1 * y0; s11 += x1 * y1;
    }
  }
  const float sc = 0.125f;  // 1/sqrt(64)
  s00 *= sc; s01 *= sc; s10 *= sc; s11 *= sc;
  float m0 = fmaxf(s00, s01), m1 = fmaxf(s10, s11);
  float e00 = __expf(s00 - m0), e01 = __expf(s01 - m0);
  float e10 = __expf(s10 - m1), e11 = __expf(s11 - m1);
  float d0 = e00 + e01, d1 = e10 + e11;
  float a00 = e00 / d0, a01 = e01 / d0, a10 = e10 / d1, a11 = e11 / d1;

  // weights = attn.mean over heads; 8 heads live in 8 adjacent lanes
  float r00 = a00, r01 = a01, r10 = a10, r11 = a11;
  #pragma unroll
  for (int mask = 1; mask < 8; mask <<= 1) {
    r00 += __shfl_xor(r00, mask);
    r01 += __shfl_xor(r01, mask);
    r10 += __shfl_xor(r10, mask);
    r11 += __shfl_xor(r11, mask);
  }
  if (h == 0) {
    float4 wv = make_float4(r00 * 0.125f, r01 * 0.125f, r10 * 0.125f, r11 * 0.125f);
    *(float4*)(wout + b * 4) = wv;
  }

  bf16_t* o0 = ctx + (b * 2) * EDIM + h * 64;
  bf16_t* o1 = o0 + EDIM;
  #pragma unroll
  for (int c = 0; c < 64; c += 8) {
    bf16x8 x0 = *(const bf16x8*)(v0 + c), x1 = *(const bf16x8*)(v1 + c);
    bf16x8 t0, t1;
    #pragma unroll
    for (int r = 0; r < 8; r++) {
      float f0 = (float)x0[r], f1 = (float)x1[r];
      t0[r] = (bf16_t)(a00 * f0 + a01 * f1);
      t1[r] = (bf16_t)(a10 * f0 + a11 * f1);
    }
    *(bf16x8*)(o0 + c) = t0;
    *(bf16x8*)(o1 + c) = t1;
  }
}

extern "C" void kernel_launch(void* const* d_in, const int* in_sizes, int n_in,
                              void* d_out, int out_size, void* d_ws, size_t ws_size,
                              hipStream_t stream) {
  (void)in_sizes; (void)n_in; (void)out_size;
  const float* vis   = (const float*)d_in[0];
  const float* txt   = (const float*)d_in[1];
  const float* w_qkv = (const float*)d_in[2];
  const float* b_qkv = (const float*)d_in[3];
  const float* w_out = (const float*)d_in[4];
  const float* b_out = (const float*)d_in[5];
  const float* w1    = (const float*)d_in[6];
  const float* b1    = (const float*)d_in[7];
  const float* w2    = (const float*)d_in[8];
  const float* b2    = (const float*)d_in[9];
  const float* gamma = (const float*)d_in[10];
  const float* beta  = (const float*)d_in[11];
  float* out_fused   = (float*)d_out;
  float* out_weights = out_fused + BATCH * OUTD;

  char* ws = (char*)d_ws;
  const size_t MB = 1024 * 1024;

  // chunked pipeline: footprint = 4MB weights + 8192*Bc bytes
  //   region1 (2048*Bc): X -> CTX
  //   region2 (6144*Bc): QKV -> H
  // Bc=16384 -> 138MB chunk working set: fits Infinity Cache (256MB) so the
  // inter-kernel intermediates stay L3-resident, while keeping the dispatch
  // chain short (round-1 lesson: Bc=8192's 51 dispatches cost ~+180us of
  // serial launch gaps and under-filled grids).
  long Bc = BATCH;
  int  nch = 1;
  while (((size_t)(4 * MB) + (size_t)(8192UL * (unsigned long)Bc) > ws_size
          || Bc > 16384) && nch < 64) {
    Bc >>= 1; nch <<= 1;
  }

  // bf16 weights: wq (786432) | w2 (131072) | wc (524288) ; bc fp32 at +3MB
  bf16_t* wq_b = (bf16_t*)ws;
  bf16_t* w2_b = wq_b + 786432;
  bf16_t* wc_b = wq_b + 917504;
  float*  bc   = (float*)(ws + 3 * MB);
  convert_w_kernel<<<448, 256, 0, stream>>>(w_qkv, w2, wq_b);
  wc_kernel<<<512, 256, 0, stream>>>(w1, w_out, wc_b);
  bc_kernel<<<2, 256, 0, stream>>>(w1, b_out, b1, bc);

  bf16_t* reg1 = (bf16_t*)(ws + 4 * MB);                     // 2048*Bc bytes
  bf16_t* reg2 = (bf16_t*)(ws + 4 * MB + (size_t)2048 * Bc); // 6144*Bc bytes

  const long Tc = 2 * Bc;  // tokens per chunk
  for (int c = 0; c < nch; c++) {
    const float* visc = vis + (long)c * Bc * EDIM;
    const float* txtc = txt + (long)c * Bc * EDIM;
    bf16_t* X   = reg1;   // Tc x 512
    bf16_t* QKV = reg2;   // Tc x 1536
    bf16_t* CTX = reg1;   // Tc x 512 (X dead after QKV gemm); == flat Bc x 1024
    bf16_t* H   = reg2;   // Bc x 512 (QKV dead after attn)

    convert_x_kernel<<<(int)(Tc / 4), 256, 0, stream>>>(visc, txtc, X);
    // QKV: (Tc x 512) @ (1536 x 512)^T
    gemm_bt_kernel<0><<<(int)(Tc / 128) * 12, 256, 0, stream>>>(
        X, wq_b, b_qkv, QKV, (int)Tc, QKVDIM, EDIM, 12);
    attn_kernel<<<(int)(Bc / 32), 256, 0, stream>>>(
        QKV, CTX, out_weights + (long)c * Bc * 4);
    // MLP1' (out_proj folded) + gelu: (Bc x 1024) @ (512 x 1024)^T
    gemm_bt_kernel<1><<<(int)(Bc / 128) * 4, 256, 0, stream>>>(
        CTX, wc_b, bc, H, (int)Bc, HIDD, CONCATD, 4);
    // MLP2 + LayerNorm fused: (Bc x 512) @ (256 x 512)^T -> LN -> fp32 out
    mlp2_ln_kernel<<<(int)(Bc / 64), 256, 0, stream>>>(
        H, w2_b, b2, gamma, beta, out_fused + (long)c * Bc * OUTD);
    ln_dummy:;
  }
}

// Round 3
// 1103.045 us; speedup vs baseline: 1.2162x; 1.0739x over previous
//
#include <hip/hip_runtime.h>
#include <hip/hip_bf16.h>
#include <math.h>

// Problem constants
#define BATCH   65536L
#define EDIM    512
#define QKVDIM  1536
#define CONCATD 1024
#define HIDD    512
#define OUTD    256

typedef __bf16 bf16_t;
typedef __bf16 bf16x8 __attribute__((ext_vector_type(8)));
typedef __bf16 bf16x4 __attribute__((ext_vector_type(4)));
typedef float  floatx4 __attribute__((ext_vector_type(4)));

static_assert(sizeof(bf16x8) == 16, "bf16x8 must be 16B");

__device__ __forceinline__ void gload16(const void* g, void* l) {
  __builtin_amdgcn_global_load_lds(
      (__attribute__((address_space(1))) void*)(g),
      (__attribute__((address_space(3))) void*)(l), 16, 0, 0);
}

// ---------- convert inputs: interleave visual/text rows -> token-major bf16 ----------
__global__ __launch_bounds__(256) void convert_x_kernel(
    const float* __restrict__ vis, const float* __restrict__ txt,
    bf16_t* __restrict__ dst) {
  long idx = (long)blockIdx.x * 256 + threadIdx.x;
  long t = idx >> 6;            // local token
  int  c = (int)(idx & 63) * 8;
  long b = t >> 1;              // local batch row
  const float* src = ((t & 1) ? txt : vis) + b * EDIM + c;
  float4 f0 = *(const float4*)src;
  float4 f1 = *(const float4*)(src + 4);
  bf16x8 o;
  o[0] = (bf16_t)f0.x; o[1] = (bf16_t)f0.y; o[2] = (bf16_t)f0.z; o[3] = (bf16_t)f0.w;
  o[4] = (bf16_t)f1.x; o[5] = (bf16_t)f1.y; o[6] = (bf16_t)f1.z; o[7] = (bf16_t)f1.w;
  *(bf16x8*)(dst + t * EDIM + c) = o;
}

// ---------- convert weights fp32 -> bf16: wq (786432) | w2 (131072) ----------
__global__ __launch_bounds__(256) void convert_w_kernel(
    const float* __restrict__ wq, const float* __restrict__ w2,
    bf16_t* __restrict__ dst) {
  long idx = ((long)blockIdx.x * 256 + threadIdx.x) * 8;  // 917504 elems total
  const long n0 = 786432;
  const float* src; long off;
  if (idx < n0) { src = wq; off = idx; }
  else          { src = w2; off = idx - n0; }
  float4 f0 = *(const float4*)(src + off);
  float4 f1 = *(const float4*)(src + off + 4);
  bf16x8 o;
  o[0] = (bf16_t)f0.x; o[1] = (bf16_t)f0.y; o[2] = (bf16_t)f0.z; o[3] = (bf16_t)f0.w;
  o[4] = (bf16_t)f1.x; o[5] = (bf16_t)f1.y; o[6] = (bf16_t)f1.z; o[7] = (bf16_t)f1.w;
  *(bf16x8*)(dst + idx) = o;
}

// ---------- fold out_proj into mlp1: Wc[n, e] (512 x 1024) bf16 ----------
__global__ __launch_bounds__(256) void wc_kernel(
    const float* __restrict__ w1, const float* __restrict__ wo,
    bf16_t* __restrict__ wc) {
  int n = blockIdx.x;
  int t = threadIdx.x;
  const float* w1v = w1 + (long)n * 1024;
  const float* w1t = w1v + 512;
  float a0 = 0.f, a1 = 0.f, a2 = 0.f, a3 = 0.f;
  for (int f = 0; f < 512; f++) {
    float wv = w1v[f], wt = w1t[f];
    float x0 = wo[f * 512 + t], x1 = wo[f * 512 + t + 256];
    a0 += wv * x0; a1 += wv * x1;
    a2 += wt * x0; a3 += wt * x1;
  }
  bf16_t* out = wc + (long)n * 1024;
  out[t]        = (bf16_t)a0;
  out[t + 256]  = (bf16_t)a1;
  out[t + 512]  = (bf16_t)a2;
  out[t + 768]  = (bf16_t)a3;
}

// ---------- folded bias: bc[n] = b1[n] + sum_f (W1[n,f]+W1[n,512+f]) * bo[f] ----------
__global__ __launch_bounds__(256) void bc_kernel(
    const float* __restrict__ w1, const float* __restrict__ bo,
    const float* __restrict__ b1, float* __restrict__ bc) {
  int n = blockIdx.x * 256 + threadIdx.x;   // grid 2 x 256
  const float* w1row = w1 + (long)n * 1024;
  float acc = b1[n];
  for (int f = 0; f < 512; f++)
    acc += (w1row[f] + w1row[512 + f]) * bo[f];
  bc[n] = acc;
}

// ---------- 256x256 GEMM, 4-slot K-ring, counted vmcnt (T3+T4): C = A @ Bt^T + bias --
// 512 threads = 8 waves (2M x 4N), 128x64 output per wave, BK=32 per K-tile.
// LDS ring: 4 slots x 32KB (A 256x32 | B 256x32 bf16), 128 KB total.
// Pipeline: iter t stages tile t+3 (4 gload16/thread) then waits vmcnt(12)
// (= 3 tiles in flight, never 0) so tile t's loads -- issued 3 iters ago --
// are complete. Raw s_barrier + asm fences (NOT __syncthreads: that would
// re-insert the vmcnt(0) drain this structure exists to remove).
// Ring safety: iter t writes slot (t+3)&3 == (t-1)&3, whose last ds_reads
// drained before iter t-1's closing barrier; read of tile t guarded by
// per-thread vmcnt(12) + barrier. K-tail: re-stage tile (t+3)&(Kt-1) into
// dead slots to keep the vmcnt literal constant (writes never re-read).
// Swizzle identical to the verified m97-style kernel:
//   physical chunk q_p at row r holds logical k-chunk q_p ^ ((r>>1)&3).
template<int EPI>
__global__ __launch_bounds__(512, 2) void gemm256_kernel(
    const bf16_t* __restrict__ A, const bf16_t* __restrict__ Bt,
    const float* __restrict__ bias, bf16_t* __restrict__ C,
    int M, int N, int K, int ntiles) {
  __shared__ __attribute__((aligned(16))) bf16_t lds[4 * 16384];
  const int bid  = blockIdx.x;
  const int mt   = bid / ntiles;
  const int nt   = bid % ntiles;
  const int tid  = threadIdx.x;
  const int wave = tid >> 6;
  const int lane = tid & 63;
  const int WM   = wave >> 2;   // 2x4 wave grid
  const int WN   = wave & 3;

  floatx4 acc[8][4];
  #pragma unroll
  for (int i = 0; i < 8; i++)
    #pragma unroll
    for (int j = 0; j < 4; j++) acc[i][j] = (floatx4){0.f, 0.f, 0.f, 0.f};

  // staging: round r covers rows r*128..r*128+127; per-wave 64 consecutive
  // 16B chunks; LDS dest = wave-uniform base + lane*16 (gload_lds semantics).
  const int srow = wave * 16 + (lane >> 2);
  const int scol = (((lane & 3) ^ ((lane >> 3) & 3)) * 8);  // pre-swizzled src
  const bf16_t* Ag0 = A  + (long)(mt * 256 + srow) * K + scol;
  const bf16_t* Ag1 = Ag0 + 128L * K;
  const bf16_t* Bg0 = Bt + (long)(nt * 256 + srow) * K + scol;
  const bf16_t* Bg1 = Bg0 + 128L * K;
  const int woff = wave * 512;  // elems

  const int m_l = lane & 15;
  const int kq  = (((lane >> 4) ^ ((m_l >> 1) & 3)) * 8);
  const int Kt  = K >> 5;
  const int Km  = Kt - 1;       // Kt is 16 or 32 (power of 2)

#define STAGE(tk, slot) do {                                    \
    const long ko_ = (long)(tk) * 32;                           \
    bf16_t* s_ = lds + (slot) * 16384;                          \
    gload16(Ag0 + ko_, s_ + woff);                              \
    gload16(Ag1 + ko_, s_ + 4096 + woff);                       \
    gload16(Bg0 + ko_, s_ + 8192 + woff);                       \
    gload16(Bg1 + ko_, s_ + 12288 + woff);                      \
  } while (0)

  STAGE(0, 0);
  STAGE(1, 1);
  STAGE(2, 2);

  for (int t = 0; t < Kt; t++) {
    STAGE((t + 3) & Km, (t + 3) & 3);
    asm volatile("s_waitcnt vmcnt(12)" ::: "memory");
    __builtin_amdgcn_s_barrier();
    asm volatile("" ::: "memory");

    const bf16_t* sl = lds + (t & 3) * 16384;
    bf16x8 a[8], b[4];
    #pragma unroll
    for (int i = 0; i < 8; i++)
      a[i] = *(const bf16x8*)&sl[(WM * 128 + i * 16 + m_l) * 32 + kq];
    #pragma unroll
    for (int j = 0; j < 4; j++)
      b[j] = *(const bf16x8*)&sl[8192 + (WN * 64 + j * 16 + m_l) * 32 + kq];
    #pragma unroll
    for (int i = 0; i < 8; i++)
      #pragma unroll
      for (int j = 0; j < 4; j++)
        acc[i][j] = __builtin_amdgcn_mfma_f32_16x16x32_bf16(a[i], b[j], acc[i][j], 0, 0, 0);

    asm volatile("" ::: "memory");
    __builtin_amdgcn_s_barrier();
    asm volatile("" ::: "memory");
  }
#undef STAGE

  // epilogue: C/D layout col=lane&15, row=(lane>>4)*4+reg  [m89-verified]
  const int col_l = lane & 15;
  const int row_q = (lane >> 4) * 4;
  float bj[4];
  #pragma unroll
  for (int j = 0; j < 4; j++)
    bj[j] = bias[nt * 256 + WN * 64 + j * 16 + col_l];
  #pragma unroll
  for (int i = 0; i < 8; i++) {
    #pragma unroll
    for (int r = 0; r < 4; r++) {
      long row = (long)(mt * 256 + WM * 128 + i * 16 + row_q + r);
      bf16_t* crow = C + row * N + nt * 256 + WN * 64 + col_l;
      #pragma unroll
      for (int j = 0; j < 4; j++) {
        float v = acc[i][j][r] + bj[j];
        if (EPI == 1) v = 0.5f * v * (1.0f + erff(v * 0.70710678118654752f));
        crow[j * 16] = (bf16_t)v;
      }
    }
  }
}

// ---------- fused MLP2 + LayerNorm: out = LN(H @ w2^T + b2) * gamma + beta ----------
__global__ __launch_bounds__(256) void mlp2_ln_kernel(
    const bf16_t* __restrict__ A,   // Bc x 512
    const bf16_t* __restrict__ Bt,  // 256 x 512
    const float* __restrict__ bias, // b2
    const float* __restrict__ gamma, const float* __restrict__ beta,
    float* __restrict__ out) {      // Bc x 256 fp32
  __shared__ __attribute__((aligned(16))) char smem[67072];
  bf16_t* sA   = (bf16_t*)smem;             // 64 x 32  (4 KB)
  bf16_t* sB   = (bf16_t*)(smem + 4096);    // 256 x 32 (16 KB)
  float*  Ot   = (float*)smem;              // 64 x 260 fp32 (overlay, 65 KB)
  float*  mu_s = (float*)(smem + 66560);    // 64 floats
  float*  rs_s = (float*)(smem + 66816);    // 64 floats

  const int tid  = threadIdx.x;
  const int wave = tid >> 6;                // wn = wave (1x4 over N)
  const int lane = tid & 63;

  floatx4 acc[4][4];
  #pragma unroll
  for (int i = 0; i < 4; i++)
    #pragma unroll
    for (int j = 0; j < 4; j++) acc[i][j] = (floatx4){0.f, 0.f, 0.f, 0.f};

  const int srow = wave * 16 + (lane >> 2);       // rows 0..63 across 4 waves
  const int scol = (((lane & 3) ^ ((lane >> 3) & 3)) * 8);
  const bf16_t* Ag = A  + ((long)blockIdx.x * 64 + srow) * 512 + scol;
  const bf16_t* Bg = Bt + (long)srow * 512 + scol;
  bf16_t* sAw = sA + wave * 16 * 32;

  const int m_l = lane & 15;
  const int kq  = (((lane >> 4) ^ ((m_l >> 1) & 3)) * 8);

  for (int k0 = 0; k0 < 512; k0 += 32) {
    __syncthreads();
    gload16(Ag + k0, sAw);
    gload16(Bg + k0,              sB + (0   + wave * 16) * 32);
    gload16(Bg + 64L * 512 + k0,  sB + (64  + wave * 16) * 32);
    gload16(Bg + 128L * 512 + k0, sB + (128 + wave * 16) * 32);
    gload16(Bg + 192L * 512 + k0, sB + (192 + wave * 16) * 32);
    __syncthreads();

    bf16x8 a[4], b[4];
    #pragma unroll
    for (int i = 0; i < 4; i++)
      a[i] = *(const bf16x8*)&sA[(i * 16 + m_l) * 32 + kq];
    #pragma unroll
    for (int j = 0; j < 4; j++)
      b[j] = *(const bf16x8*)&sB[(wave * 64 + j * 16 + m_l) * 32 + kq];
    #pragma unroll
    for (int i = 0; i < 4; i++)
      #pragma unroll
      for (int j = 0; j < 4; j++)
        acc[i][j] = __builtin_amdgcn_mfma_f32_16x16x32_bf16(a[i], b[j], acc[i][j], 0, 0, 0);
  }

  // epilogue: scatter fp32 (acc + bias) into LDS O-tile
  const int col_l = lane & 15;
  const int row_q = (lane >> 4) * 4;
  float bj[4];
  #pragma unroll
  for (int j = 0; j < 4; j++)
    bj[j] = bias[wave * 64 + j * 16 + col_l];
  __syncthreads();  // sA/sB reads complete before overlay
  #pragma unroll
  for (int i = 0; i < 4; i++)
    #pragma unroll
    for (int r = 0; r < 4; r++)
      #pragma unroll
      for (int j = 0; j < 4; j++)
        Ot[(i * 16 + row_q + r) * 260 + wave * 64 + j * 16 + col_l] =
            acc[i][j][r] + bj[j];
  __syncthreads();

  // row stats: thread t covers row t>>2, quarter t&3 (64 cols)
  {
    int row = tid >> 2, q = tid & 3;
    const float* p = Ot + row * 260 + q * 64;
    float s = 0.f, s2 = 0.f;
    #pragma unroll
    for (int c = 0; c < 64; c += 4) {
      float4 v = *(const float4*)(p + c);
      s  += v.x + v.y + v.z + v.w;
      s2 += v.x * v.x + v.y * v.y + v.z * v.z + v.w * v.w;
    }
    s  += __shfl_xor(s, 1);  s  += __shfl_xor(s, 2);
    s2 += __shfl_xor(s2, 1); s2 += __shfl_xor(s2, 2);
    if (q == 0) {
      float mu  = s * (1.0f / 256.0f);
      float var = s2 * (1.0f / 256.0f) - mu * mu;
      mu_s[row] = mu;
      rs_s[row] = rsqrtf(var + 1e-5f);
    }
  }
  __syncthreads();

  // normalize + coalesced write: wave handles rows rr*4+wave; 1 KB/row/wave
  float4 g  = *(const float4*)(gamma + lane * 4);
  float4 be = *(const float4*)(beta + lane * 4);
  #pragma unroll
  for (int rr = 0; rr < 16; rr++) {
    int row = rr * 4 + wave;
    float mu = mu_s[row], rs = rs_s[row];
    float4 v = *(const float4*)(Ot + row * 260 + lane * 4);
    float4 res;
    res.x = (v.x - mu) * rs * g.x + be.x;
    res.y = (v.y - mu) * rs * g.y + be.y;
    res.z = (v.z - mu) * rs * g.z + be.z;
    res.w = (v.w - mu) * rs * g.w + be.w;
    *(float4*)(out + ((long)blockIdx.x * 64 + row) * 256 + lane * 4) = res;
  }
}

// ---------- attention: per (row, head) 2x2 softmax + ctx; head-mean weights ----------
__global__ __launch_bounds__(256) void attn_kernel(
    const bf16_t* __restrict__ qkv, bf16_t* __restrict__ ctx,
    float* __restrict__ wout) {
  long idx = (long)blockIdx.x * 256 + threadIdx.x;
  long b = idx >> 3;   // local batch row
  int  h = (int)(idx & 7);
  const bf16_t* base = qkv + (b * 2) * QKVDIM + h * 64;
  const bf16_t* q0 = base;
  const bf16_t* q1 = base + QKVDIM;
  const bf16_t* k0 = base + EDIM;
  const bf16_t* k1 = base + EDIM + QKVDIM;
  const bf16_t* v0 = base + 2 * EDIM;
  const bf16_t* v1 = base + 2 * EDIM + QKVDIM;

  float s00 = 0.f, s01 = 0.f, s10 = 0.f, s11 = 0.f;
  #pragma unroll
  for (int c = 0; c < 64; c += 8) {
    bf16x8 a0 = *(const bf16x8*)(q0 + c), a1 = *(const bf16x8*)(q1 + c);
    bf16x8 c0 = *(const bf16x8*)(k0 + c), c1 = *(const bf16x8*)(k1 + c);
    #pragma unroll
    for (int r = 0; r < 8; r++) {
      float x0 = (float)a0[r], x1 = (float)a1[r];
      float y0 = (float)c0[r], y1 = (float)c1[r];
      s00 += x0 * y0; s01 += x0 * y1; s10 += x1 * y0; s11 += x1 * y1;
    }
  }
  const float sc = 0.125f;  // 1/sqrt(64)
  s00 *= sc; s01 *= sc; s10 *= sc; s11 *= sc;
  float m0 = fmaxf(s00, s01), m1 = fmaxf(s10, s11);
  float e00 = __expf(s00 - m0), e01 = __expf(s01 - m0);
  float e10 = __expf(s10 - m1), e11 = __expf(s11 - m1);
  float d0 = e00 + e01, d1 = e10 + e11;
  float a00 = e00 / d0, a01 = e01 / d0, a10 = e10 / d1, a11 = e11 / d1;

  // weights = attn.mean over heads; 8 heads live in 8 adjacent lanes
  float r00 = a00, r01 = a01, r10 = a10, r11 = a11;
  #pragma unroll
  for (int mask = 1; mask < 8; mask <<= 1) {
    r00 += __shfl_xor(r00, mask);
    r01 += __shfl_xor(r01, mask);
    r10 += __shfl_xor(r10, mask);
    r11 += __shfl_xor(r11, mask);
  }
  if (h == 0) {
    float4 wv = make_float4(r00 * 0.125f, r01 * 0.125f, r10 * 0.125f, r11 * 0.125f);
    *(float4*)(wout + b * 4) = wv;
  }

  bf16_t* o0 = ctx + (b * 2) * EDIM + h * 64;
  bf16_t* o1 = o0 + EDIM;
  #pragma unroll
  for (int c = 0; c < 64; c += 8) {
    bf16x8 x0 = *(const bf16x8*)(v0 + c), x1 = *(const bf16x8*)(v1 + c);
    bf16x8 t0, t1;
    #pragma unroll
    for (int r = 0; r < 8; r++) {
      float f0 = (float)x0[r], f1 = (float)x1[r];
      t0[r] = (bf16_t)(a00 * f0 + a01 * f1);
      t1[r] = (bf16_t)(a10 * f0 + a11 * f1);
    }
    *(bf16x8*)(o0 + c) = t0;
    *(bf16x8*)(o1 + c) = t1;
  }
}

extern "C" void kernel_launch(void* const* d_in, const int* in_sizes, int n_in,
                              void* d_out, int out_size, void* d_ws, size_t ws_size,
                              hipStream_t stream) {
  (void)in_sizes; (void)n_in; (void)out_size;
  const float* vis   = (const float*)d_in[0];
  const float* txt   = (const float*)d_in[1];
  const float* w_qkv = (const float*)d_in[2];
  const float* b_qkv = (const float*)d_in[3];
  const float* w_out = (const float*)d_in[4];
  const float* b_out = (const float*)d_in[5];
  const float* w1    = (const float*)d_in[6];
  const float* b1    = (const float*)d_in[7];
  const float* w2    = (const float*)d_in[8];
  const float* b2    = (const float*)d_in[9];
  const float* gamma = (const float*)d_in[10];
  const float* beta  = (const float*)d_in[11];
  float* out_fused   = (float*)d_out;
  float* out_weights = out_fused + BATCH * OUTD;

  char* ws = (char*)d_ws;
  const size_t MB = 1024 * 1024;

  // chunked pipeline: footprint = 4MB weights + 8192*Bc bytes
  //   region1 (2048*Bc): X -> CTX
  //   region2 (6144*Bc): QKV -> H
  // Bc=32768 (2 chunks): round-1/2 lesson -- smaller chunks do NOT speed up
  // the GEMMs (not BW-bound) and each extra chunk costs dispatch-gap time.
  long Bc = BATCH;
  int  nch = 1;
  while (((size_t)(4 * MB) + (size_t)(8192UL * (unsigned long)Bc) > ws_size
          || Bc > 32768) && nch < 64) {
    Bc >>= 1; nch <<= 1;
  }

  // bf16 weights: wq (786432) | w2 (131072) | wc (524288) ; bc fp32 at +3MB
  bf16_t* wq_b = (bf16_t*)ws;
  bf16_t* w2_b = wq_b + 786432;
  bf16_t* wc_b = wq_b + 917504;
  float*  bc   = (float*)(ws + 3 * MB);
  convert_w_kernel<<<448, 256, 0, stream>>>(w_qkv, w2, wq_b);
  wc_kernel<<<512, 256, 0, stream>>>(w1, w_out, wc_b);
  bc_kernel<<<2, 256, 0, stream>>>(w1, b_out, b1, bc);

  bf16_t* reg1 = (bf16_t*)(ws + 4 * MB);                     // 2048*Bc bytes
  bf16_t* reg2 = (bf16_t*)(ws + 4 * MB + (size_t)2048 * Bc); // 6144*Bc bytes

  const long Tc = 2 * Bc;  // tokens per chunk
  for (int c = 0; c < nch; c++) {
    const float* visc = vis + (long)c * Bc * EDIM;
    const float* txtc = txt + (long)c * Bc * EDIM;
    bf16_t* X   = reg1;   // Tc x 512
    bf16_t* QKV = reg2;   // Tc x 1536
    bf16_t* CTX = reg1;   // Tc x 512 (X dead after QKV gemm); == flat Bc x 1024
    bf16_t* H   = reg2;   // Bc x 512 (QKV dead after attn)

    convert_x_kernel<<<(int)(Tc / 4), 256, 0, stream>>>(visc, txtc, X);
    // QKV: (Tc x 512) @ (1536 x 512)^T  -- 256x256 tiles, 6 n-tiles
    gemm256_kernel<0><<<(int)(Tc / 256) * 6, 512, 0, stream>>>(
        X, wq_b, b_qkv, QKV, (int)Tc, QKVDIM, EDIM, 6);
    attn_kernel<<<(int)(Bc / 32), 256, 0, stream>>>(
        QKV, CTX, out_weights + (long)c * Bc * 4);
    // MLP1' (out_proj folded) + gelu: (Bc x 1024) @ (512 x 1024)^T -- 2 n-tiles
    gemm256_kernel<1><<<(int)(Bc / 256) * 2, 512, 0, stream>>>(
        CTX, wc_b, bc, H, (int)Bc, HIDD, CONCATD, 2);
    // MLP2 + LayerNorm fused: (Bc x 512) @ (256 x 512)^T -> LN -> fp32 out
    mlp2_ln_kernel<<<(int)(Bc / 64), 256, 0, stream>>>(
        H, w2_b, b2, gamma, beta, out_fused + (long)c * Bc * OUTD);
  }
}

// Round 4
// 872.118 us; speedup vs baseline: 1.5383x; 1.2648x over previous
//
#include <hip/hip_runtime.h>
#include <hip/hip_bf16.h>
#include <math.h>

// Problem constants
#define BATCH   65536L
#define EDIM    512
#define QKVDIM  1536
#define CONCATD 1024
#define HIDD    512
#define OUTD    256

typedef __bf16 bf16_t;
typedef __bf16 bf16x8 __attribute__((ext_vector_type(8)));
typedef __bf16 bf16x4 __attribute__((ext_vector_type(4)));
typedef float  floatx4 __attribute__((ext_vector_type(4)));

static_assert(sizeof(bf16x8) == 16, "bf16x8 must be 16B");

__device__ __forceinline__ void gload16(const void* g, void* l) {
  __builtin_amdgcn_global_load_lds(
      (__attribute__((address_space(1))) void*)(g),
      (__attribute__((address_space(3))) void*)(l), 16, 0, 0);
}

// ---------- convert inputs: interleave visual/text rows -> token-major bf16 ----------
__global__ __launch_bounds__(256) void convert_x_kernel(
    const float* __restrict__ vis, const float* __restrict__ txt,
    bf16_t* __restrict__ dst) {
  long idx = (long)blockIdx.x * 256 + threadIdx.x;
  long t = idx >> 6;            // local token
  int  c = (int)(idx & 63) * 8;
  long b = t >> 1;              // local batch row
  const float* src = ((t & 1) ? txt : vis) + b * EDIM + c;
  float4 f0 = *(const float4*)src;
  float4 f1 = *(const float4*)(src + 4);
  bf16x8 o;
  o[0] = (bf16_t)f0.x; o[1] = (bf16_t)f0.y; o[2] = (bf16_t)f0.z; o[3] = (bf16_t)f0.w;
  o[4] = (bf16_t)f1.x; o[5] = (bf16_t)f1.y; o[6] = (bf16_t)f1.z; o[7] = (bf16_t)f1.w;
  *(bf16x8*)(dst + t * EDIM + c) = o;
}

// ---------- convert weights fp32 -> bf16: wq (786432) | w2 (131072) ----------
__global__ __launch_bounds__(256) void convert_w_kernel(
    const float* __restrict__ wq, const float* __restrict__ w2,
    bf16_t* __restrict__ dst) {
  long idx = ((long)blockIdx.x * 256 + threadIdx.x) * 8;  // 917504 elems total
  const long n0 = 786432;
  const float* src; long off;
  if (idx < n0) { src = wq; off = idx; }
  else          { src = w2; off = idx - n0; }
  float4 f0 = *(const float4*)(src + off);
  float4 f1 = *(const float4*)(src + off + 4);
  bf16x8 o;
  o[0] = (bf16_t)f0.x; o[1] = (bf16_t)f0.y; o[2] = (bf16_t)f0.z; o[3] = (bf16_t)f0.w;
  o[4] = (bf16_t)f1.x; o[5] = (bf16_t)f1.y; o[6] = (bf16_t)f1.z; o[7] = (bf16_t)f1.w;
  *(bf16x8*)(dst + idx) = o;
}

// ---------- fold out_proj into mlp1: Wc[n, e] (512 x 1024) bf16 ----------
__global__ __launch_bounds__(256) void wc_kernel(
    const float* __restrict__ w1, const float* __restrict__ wo,
    bf16_t* __restrict__ wc) {
  int n = blockIdx.x;
  int t = threadIdx.x;
  const float* w1v = w1 + (long)n * 1024;
  const float* w1t = w1v + 512;
  float a0 = 0.f, a1 = 0.f, a2 = 0.f, a3 = 0.f;
  for (int f = 0; f < 512; f++) {
    float wv = w1v[f], wt = w1t[f];
    float x0 = wo[f * 512 + t], x1 = wo[f * 512 + t + 256];
    a0 += wv * x0; a1 += wv * x1;
    a2 += wt * x0; a3 += wt * x1;
  }
  bf16_t* out = wc + (long)n * 1024;
  out[t]        = (bf16_t)a0;
  out[t + 256]  = (bf16_t)a1;
  out[t + 512]  = (bf16_t)a2;
  out[t + 768]  = (bf16_t)a3;
}

// ---------- folded bias: bc[n] = b1[n] + sum_f (W1[n,f]+W1[n,512+f]) * bo[f] ----------
__global__ __launch_bounds__(256) void bc_kernel(
    const float* __restrict__ w1, const float* __restrict__ bo,
    const float* __restrict__ b1, float* __restrict__ bc) {
  int n = blockIdx.x * 256 + threadIdx.x;   // grid 2 x 256
  const float* w1row = w1 + (long)n * 1024;
  float acc = b1[n];
  for (int f = 0; f < 512; f++)
    acc += (w1row[f] + w1row[512 + f]) * bo[f];
  bc[n] = acc;
}

// ---------- 256x256 GEMM, 4-slot K-ring, counted vmcnt (T3+T4): C = A @ Bt^T + bias --
// 512 threads = 8 waves (2M x 4N), 128x64 output per wave, BK=32 per K-tile.
// LDS ring: 4 slots x 32KB, vmcnt(12) = 3 tiles in flight (never 0).
// NEW (round 4): XCD-aware block swizzle. Logical block L = mt*ntiles+nt;
// dispatch slot i runs on XCD i%8 (CP round-robin), so map
// L = (i%8)*(nwg/8) + i/8: each XCD walks a CONTIGUOUS logical range ->
// the ntiles n-tile sharers of an A-panel run on the SAME XCD, A slice
// (~1.4MB) + full B (<=1.5MB) stay resident in that XCD's 4MB L2, killing
// the 4x A-refetch seen in round 3 (FETCH 268MB vs 67MB compulsory).
template<int EPI>
__global__ __launch_bounds__(512, 2) void gemm256_kernel(
    const bf16_t* __restrict__ A, const bf16_t* __restrict__ Bt,
    const float* __restrict__ bias, bf16_t* __restrict__ C,
    int M, int N, int K, int ntiles) {
  __shared__ __attribute__((aligned(16))) bf16_t lds[4 * 16384];
  int bid = blockIdx.x;
  {
    const int nwg = gridDim.x;
    if ((nwg & 7) == 0) bid = (bid & 7) * (nwg >> 3) + (bid >> 3);
  }
  const int mt   = bid / ntiles;
  const int nt   = bid % ntiles;
  const int tid  = threadIdx.x;
  const int wave = tid >> 6;
  const int lane = tid & 63;
  const int WM   = wave >> 2;   // 2x4 wave grid
  const int WN   = wave & 3;

  floatx4 acc[8][4];
  #pragma unroll
  for (int i = 0; i < 8; i++)
    #pragma unroll
    for (int j = 0; j < 4; j++) acc[i][j] = (floatx4){0.f, 0.f, 0.f, 0.f};

  const int srow = wave * 16 + (lane >> 2);
  const int scol = (((lane & 3) ^ ((lane >> 3) & 3)) * 8);  // pre-swizzled src
  const bf16_t* Ag0 = A  + (long)(mt * 256 + srow) * K + scol;
  const bf16_t* Ag1 = Ag0 + 128L * K;
  const bf16_t* Bg0 = Bt + (long)(nt * 256 + srow) * K + scol;
  const bf16_t* Bg1 = Bg0 + 128L * K;
  const int woff = wave * 512;  // elems

  const int m_l = lane & 15;
  const int kq  = (((lane >> 4) ^ ((m_l >> 1) & 3)) * 8);
  const int Kt  = K >> 5;
  const int Km  = Kt - 1;       // Kt is 16 or 32 (power of 2)

#define STAGE(tk, slot) do {                                    \
    const long ko_ = (long)(tk) * 32;                           \
    bf16_t* s_ = lds + (slot) * 16384;                          \
    gload16(Ag0 + ko_, s_ + woff);                              \
    gload16(Ag1 + ko_, s_ + 4096 + woff);                       \
    gload16(Bg0 + ko_, s_ + 8192 + woff);                       \
    gload16(Bg1 + ko_, s_ + 12288 + woff);                      \
  } while (0)

  STAGE(0, 0);
  STAGE(1, 1);
  STAGE(2, 2);

  for (int t = 0; t < Kt; t++) {
    STAGE((t + 3) & Km, (t + 3) & 3);
    asm volatile("s_waitcnt vmcnt(12)" ::: "memory");
    __builtin_amdgcn_s_barrier();
    asm volatile("" ::: "memory");

    const bf16_t* sl = lds + (t & 3) * 16384;
    bf16x8 a[8], b[4];
    #pragma unroll
    for (int i = 0; i < 8; i++)
      a[i] = *(const bf16x8*)&sl[(WM * 128 + i * 16 + m_l) * 32 + kq];
    #pragma unroll
    for (int j = 0; j < 4; j++)
      b[j] = *(const bf16x8*)&sl[8192 + (WN * 64 + j * 16 + m_l) * 32 + kq];
    #pragma unroll
    for (int i = 0; i < 8; i++)
      #pragma unroll
      for (int j = 0; j < 4; j++)
        acc[i][j] = __builtin_amdgcn_mfma_f32_16x16x32_bf16(a[i], b[j], acc[i][j], 0, 0, 0);

    asm volatile("" ::: "memory");
    __builtin_amdgcn_s_barrier();
    asm volatile("" ::: "memory");
  }
#undef STAGE

  // epilogue: C/D layout col=lane&15, row=(lane>>4)*4+reg  [m89-verified]
  const int col_l = lane & 15;
  const int row_q = (lane >> 4) * 4;
  float bj[4];
  #pragma unroll
  for (int j = 0; j < 4; j++)
    bj[j] = bias[nt * 256 + WN * 64 + j * 16 + col_l];
  #pragma unroll
  for (int i = 0; i < 8; i++) {
    #pragma unroll
    for (int r = 0; r < 4; r++) {
      long row = (long)(mt * 256 + WM * 128 + i * 16 + row_q + r);
      bf16_t* crow = C + row * N + nt * 256 + WN * 64 + col_l;
      #pragma unroll
      for (int j = 0; j < 4; j++) {
        float v = acc[i][j][r] + bj[j];
        if (EPI == 1) v = 0.5f * v * (1.0f + erff(v * 0.70710678118654752f));
        crow[j * 16] = (bf16_t)v;
      }
    }
  }
}

// ---------- fused MLP2 + LayerNorm: out = LN(H @ w2^T + b2) * gamma + beta ----------
__global__ __launch_bounds__(256) void mlp2_ln_kernel(
    const bf16_t* __restrict__ A,   // Bc x 512
    const bf16_t* __restrict__ Bt,  // 256 x 512
    const float* __restrict__ bias, // b2
    const float* __restrict__ gamma, const float* __restrict__ beta,
    float* __restrict__ out) {      // Bc x 256 fp32
  __shared__ __attribute__((aligned(16))) char smem[67072];
  bf16_t* sA   = (bf16_t*)smem;             // 64 x 32  (4 KB)
  bf16_t* sB   = (bf16_t*)(smem + 4096);    // 256 x 32 (16 KB)
  float*  Ot   = (float*)smem;              // 64 x 260 fp32 (overlay, 65 KB)
  float*  mu_s = (float*)(smem + 66560);    // 64 floats
  float*  rs_s = (float*)(smem + 66816);    // 64 floats

  const int tid  = threadIdx.x;
  const int wave = tid >> 6;                // wn = wave (1x4 over N)
  const int lane = tid & 63;

  floatx4 acc[4][4];
  #pragma unroll
  for (int i = 0; i < 4; i++)
    #pragma unroll
    for (int j = 0; j < 4; j++) acc[i][j] = (floatx4){0.f, 0.f, 0.f, 0.f};

  const int srow = wave * 16 + (lane >> 2);       // rows 0..63 across 4 waves
  const int scol = (((lane & 3) ^ ((lane >> 3) & 3)) * 8);
  const bf16_t* Ag = A  + ((long)blockIdx.x * 64 + srow) * 512 + scol;
  const bf16_t* Bg = Bt + (long)srow * 512 + scol;
  bf16_t* sAw = sA + wave * 16 * 32;

  const int m_l = lane & 15;
  const int kq  = (((lane >> 4) ^ ((m_l >> 1) & 3)) * 8);

  for (int k0 = 0; k0 < 512; k0 += 32) {
    __syncthreads();
    gload16(Ag + k0, sAw);
    gload16(Bg + k0,              sB + (0   + wave * 16) * 32);
    gload16(Bg + 64L * 512 + k0,  sB + (64  + wave * 16) * 32);
    gload16(Bg + 128L * 512 + k0, sB + (128 + wave * 16) * 32);
    gload16(Bg + 192L * 512 + k0, sB + (192 + wave * 16) * 32);
    __syncthreads();

    bf16x8 a[4], b[4];
    #pragma unroll
    for (int i = 0; i < 4; i++)
      a[i] = *(const bf16x8*)&sA[(i * 16 + m_l) * 32 + kq];
    #pragma unroll
    for (int j = 0; j < 4; j++)
      b[j] = *(const bf16x8*)&sB[(wave * 64 + j * 16 + m_l) * 32 + kq];
    #pragma unroll
    for (int i = 0; i < 4; i++)
      #pragma unroll
      for (int j = 0; j < 4; j++)
        acc[i][j] = __builtin_amdgcn_mfma_f32_16x16x32_bf16(a[i], b[j], acc[i][j], 0, 0, 0);
  }

  // epilogue: scatter fp32 (acc + bias) into LDS O-tile
  const int col_l = lane & 15;
  const int row_q = (lane >> 4) * 4;
  float bj[4];
  #pragma unroll
  for (int j = 0; j < 4; j++)
    bj[j] = bias[wave * 64 + j * 16 + col_l];
  __syncthreads();  // sA/sB reads complete before overlay
  #pragma unroll
  for (int i = 0; i < 4; i++)
    #pragma unroll
    for (int r = 0; r < 4; r++)
      #pragma unroll
      for (int j = 0; j < 4; j++)
        Ot[(i * 16 + row_q + r) * 260 + wave * 64 + j * 16 + col_l] =
            acc[i][j][r] + bj[j];
  __syncthreads();

  // row stats: thread t covers row t>>2, quarter t&3 (64 cols)
  {
    int row = tid >> 2, q = tid & 3;
    const float* p = Ot + row * 260 + q * 64;
    float s = 0.f, s2 = 0.f;
    #pragma unroll
    for (int c = 0; c < 64; c += 4) {
      float4 v = *(const float4*)(p + c);
      s  += v.x + v.y + v.z + v.w;
      s2 += v.x * v.x + v.y * v.y + v.z * v.z + v.w * v.w;
    }
    s  += __shfl_xor(s, 1);  s  += __shfl_xor(s, 2);
    s2 += __shfl_xor(s2, 1); s2 += __shfl_xor(s2, 2);
    if (q == 0) {
      float mu  = s * (1.0f / 256.0f);
      float var = s2 * (1.0f / 256.0f) - mu * mu;
      mu_s[row] = mu;
      rs_s[row] = rsqrtf(var + 1e-5f);
    }
  }
  __syncthreads();

  // normalize + coalesced write: wave handles rows rr*4+wave; 1 KB/row/wave
  float4 g  = *(const float4*)(gamma + lane * 4);
  float4 be = *(const float4*)(beta + lane * 4);
  #pragma unroll
  for (int rr = 0; rr < 16; rr++) {
    int row = rr * 4 + wave;
    float mu = mu_s[row], rs = rs_s[row];
    float4 v = *(const float4*)(Ot + row * 260 + lane * 4);
    float4 res;
    res.x = (v.x - mu) * rs * g.x + be.x;
    res.y = (v.y - mu) * rs * g.y + be.y;
    res.z = (v.z - mu) * rs * g.z + be.z;
    res.w = (v.w - mu) * rs * g.w + be.w;
    *(float4*)(out + ((long)blockIdx.x * 64 + row) * 256 + lane * 4) = res;
  }
}

// ---------- attention (round 4 rewrite): one WAVE per batch row ----------
// Lanes cover the full 512-elem token row (64 lanes x 8 elems); head = lane>>3.
// All 6 QKV row-reads and both ctx stores are fully-coalesced 1KB wave
// transactions (round-3 layout read 16B per 128B line and partially wrote
// 64B sectors: FETCH 1.8x, WRITE 2x amplified).
__global__ __launch_bounds__(256) void attn_kernel(
    const bf16_t* __restrict__ qkv, bf16_t* __restrict__ ctx,
    float* __restrict__ wout) {
  const int  lane = threadIdx.x & 63;
  const long b    = (long)blockIdx.x * 4 + (threadIdx.x >> 6);
  const bf16_t* base = qkv + b * 2 * QKVDIM;
  const int off = lane * 8;

  bf16x8 q0 = *(const bf16x8*)(base + off);
  bf16x8 k0 = *(const bf16x8*)(base + EDIM + off);
  bf16x8 v0 = *(const bf16x8*)(base + 2 * EDIM + off);
  bf16x8 q1 = *(const bf16x8*)(base + QKVDIM + off);
  bf16x8 k1 = *(const bf16x8*)(base + QKVDIM + EDIM + off);
  bf16x8 v1 = *(const bf16x8*)(base + QKVDIM + 2 * EDIM + off);

  float s00 = 0.f, s01 = 0.f, s10 = 0.f, s11 = 0.f;
  #pragma unroll
  for (int r = 0; r < 8; r++) {
    float x0 = (float)q0[r], x1 = (float)q1[r];
    float y0 = (float)k0[r], y1 = (float)k1[r];
    s00 += x0 * y0; s01 += x0 * y1; s10 += x1 * y0; s11 += x1 * y1;
  }
  // reduce within the 8-lane head group (lanes h*8 .. h*8+7)
  #pragma unroll
  for (int m = 1; m < 8; m <<= 1) {
    s00 += __shfl_xor(s00, m); s01 += __shfl_xor(s01, m);
    s10 += __shfl_xor(s10, m); s11 += __shfl_xor(s11, m);
  }
  const float sc = 0.125f;  // 1/sqrt(64)
  s00 *= sc; s01 *= sc; s10 *= sc; s11 *= sc;
  float m0 = fmaxf(s00, s01), m1 = fmaxf(s10, s11);
  float e00 = __expf(s00 - m0), e01 = __expf(s01 - m0);
  float e10 = __expf(s10 - m1), e11 = __expf(s11 - m1);
  float d0 = e00 + e01, d1 = e10 + e11;
  float a00 = e00 / d0, a01 = e01 / d0, a10 = e10 / d1, a11 = e11 / d1;

  // head-mean: sum across the 8 head groups (masks 8,16,32)
  float r00 = a00, r01 = a01, r10 = a10, r11 = a11;
  #pragma unroll
  for (int m = 8; m < 64; m <<= 1) {
    r00 += __shfl_xor(r00, m); r01 += __shfl_xor(r01, m);
    r10 += __shfl_xor(r10, m); r11 += __shfl_xor(r11, m);
  }
  if (lane == 0) {
    float4 wv = make_float4(r00 * 0.125f, r01 * 0.125f, r10 * 0.125f, r11 * 0.125f);
    *(float4*)(wout + b * 4) = wv;
  }

  bf16x8 t0, t1;
  #pragma unroll
  for (int r = 0; r < 8; r++) {
    float f0 = (float)v0[r], f1 = (float)v1[r];
    t0[r] = (bf16_t)(a00 * f0 + a01 * f1);
    t1[r] = (bf16_t)(a10 * f0 + a11 * f1);
  }
  *(bf16x8*)(ctx + (b * 2) * EDIM + off)     = t0;
  *(bf16x8*)(ctx + (b * 2 + 1) * EDIM + off) = t1;
}

extern "C" void kernel_launch(void* const* d_in, const int* in_sizes, int n_in,
                              void* d_out, int out_size, void* d_ws, size_t ws_size,
                              hipStream_t stream) {
  (void)in_sizes; (void)n_in; (void)out_size;
  const float* vis   = (const float*)d_in[0];
  const float* txt   = (const float*)d_in[1];
  const float* w_qkv = (const float*)d_in[2];
  const float* b_qkv = (const float*)d_in[3];
  const float* w_out = (const float*)d_in[4];
  const float* b_out = (const float*)d_in[5];
  const float* w1    = (const float*)d_in[6];
  const float* b1    = (const float*)d_in[7];
  const float* w2    = (const float*)d_in[8];
  const float* b2    = (const float*)d_in[9];
  const float* gamma = (const float*)d_in[10];
  const float* beta  = (const float*)d_in[11];
  float* out_fused   = (float*)d_out;
  float* out_weights = out_fused + BATCH * OUTD;

  char* ws = (char*)d_ws;
  const size_t MB = 1024 * 1024;

  // chunked pipeline: footprint = 4MB weights + 8192*Bc bytes
  //   region1 (2048*Bc): X -> CTX
  //   region2 (6144*Bc): QKV -> H
  // Bc=32768 (2 chunks): smaller chunks don't help (GEMMs aren't BW-bound on
  // intermediates) and each extra chunk costs dispatch-gap time.
  long Bc = BATCH;
  int  nch = 1;
  while (((size_t)(4 * MB) + (size_t)(8192UL * (unsigned long)Bc) > ws_size
          || Bc > 32768) && nch < 64) {
    Bc >>= 1; nch <<= 1;
  }

  // bf16 weights: wq (786432) | w2 (131072) | wc (524288) ; bc fp32 at +3MB
  bf16_t* wq_b = (bf16_t*)ws;
  bf16_t* w2_b = wq_b + 786432;
  bf16_t* wc_b = wq_b + 917504;
  float*  bc   = (float*)(ws + 3 * MB);
  convert_w_kernel<<<448, 256, 0, stream>>>(w_qkv, w2, wq_b);
  wc_kernel<<<512, 256, 0, stream>>>(w1, w_out, wc_b);
  bc_kernel<<<2, 256, 0, stream>>>(w1, b_out, b1, bc);

  bf16_t* reg1 = (bf16_t*)(ws + 4 * MB);                     // 2048*Bc bytes
  bf16_t* reg2 = (bf16_t*)(ws + 4 * MB + (size_t)2048 * Bc); // 6144*Bc bytes

  const long Tc = 2 * Bc;  // tokens per chunk
  for (int c = 0; c < nch; c++) {
    const float* visc = vis + (long)c * Bc * EDIM;
    const float* txtc = txt + (long)c * Bc * EDIM;
    bf16_t* X   = reg1;   // Tc x 512
    bf16_t* QKV = reg2;   // Tc x 1536
    bf16_t* CTX = reg1;   // Tc x 512 (X dead after QKV gemm); == flat Bc x 1024
    bf16_t* H   = reg2;   // Bc x 512 (QKV dead after attn)

    convert_x_kernel<<<(int)(Tc / 4), 256, 0, stream>>>(visc, txtc, X);
    // QKV: (Tc x 512) @ (1536 x 512)^T  -- 256x256 tiles, 6 n-tiles
    gemm256_kernel<0><<<(int)(Tc / 256) * 6, 512, 0, stream>>>(
        X, wq_b, b_qkv, QKV, (int)Tc, QKVDIM, EDIM, 6);
    attn_kernel<<<(int)(Bc / 4), 256, 0, stream>>>(
        QKV, CTX, out_weights + (long)c * Bc * 4);
    // MLP1' (out_proj folded) + gelu: (Bc x 1024) @ (512 x 1024)^T -- 2 n-tiles
    gemm256_kernel<1><<<(int)(Bc / 256) * 2, 512, 0, stream>>>(
        CTX, wc_b, bc, H, (int)Bc, HIDD, CONCATD, 2);
    // MLP2 + LayerNorm fused: (Bc x 512) @ (256 x 512)^T -> LN -> fp32 out
    mlp2_ln_kernel<<<(int)(Bc / 64), 256, 0, stream>>>(
        H, w2_b, b2, gamma, beta, out_fused + (long)c * Bc * OUTD);
  }
}